// Round 1
// baseline (172.541 us; speedup 1.0000x reference)
//
#include <hip/hip_runtime.h>

#define NUM_BINS 64
#define NPIX (256 * 256)
#define NIMG 16
#define HIST_SIZE (NUM_BINS * NUM_BINS)
#define OUT_ELEMS (NIMG * HIST_SIZE)
#define BLOCKS_PER_IMG 32

// order-preserving float <-> uint mapping for atomicMin/Max on floats
__device__ __forceinline__ unsigned int f2o(float f) {
    unsigned int b = __float_as_uint(f);
    return (b & 0x80000000u) ? ~b : (b | 0x80000000u);
}
__device__ __forceinline__ float o2f(unsigned int u) {
    return __uint_as_float((u & 0x80000000u) ? (u ^ 0x80000000u) : ~u);
}

// ws layout: [0]=min_ref [1]=max_ref [2]=min_tar [3]=max_tar (ordered-uint)
__global__ void init_kernel(float* __restrict__ out, unsigned int* __restrict__ ws) {
    int i = blockIdx.x * blockDim.x + threadIdx.x;
    if (i < OUT_ELEMS) out[i] = 0.0f;
    if (i == 0) {
        ws[0] = 0xFFFFFFFFu; ws[1] = 0u;
        ws[2] = 0xFFFFFFFFu; ws[3] = 0u;
    }
}

__global__ __launch_bounds__(256) void minmax_kernel(
        const float4* __restrict__ ref4, const float4* __restrict__ tar4,
        unsigned int* __restrict__ ws) {
    const int tid = blockIdx.x * blockDim.x + threadIdx.x;
    const int stride = gridDim.x * blockDim.x;
    const int n4 = (NIMG * NPIX) / 4;
    float mnr = 3.0e38f, mxr = -3.0e38f, mnt = 3.0e38f, mxt = -3.0e38f;
    for (int i = tid; i < n4; i += stride) {
        float4 a = ref4[i];
        mnr = fminf(mnr, fminf(fminf(a.x, a.y), fminf(a.z, a.w)));
        mxr = fmaxf(mxr, fmaxf(fmaxf(a.x, a.y), fmaxf(a.z, a.w)));
        float4 b = tar4[i];
        mnt = fminf(mnt, fminf(fminf(b.x, b.y), fminf(b.z, b.w)));
        mxt = fmaxf(mxt, fmaxf(fmaxf(b.x, b.y), fmaxf(b.z, b.w)));
    }
    #pragma unroll
    for (int off = 32; off > 0; off >>= 1) {  // wave64 butterfly
        mnr = fminf(mnr, __shfl_down(mnr, off));
        mxr = fmaxf(mxr, __shfl_down(mxr, off));
        mnt = fminf(mnt, __shfl_down(mnt, off));
        mxt = fmaxf(mxt, __shfl_down(mxt, off));
    }
    __shared__ float s[4][4];  // [stat][wave], 4 waves per 256-thr block
    const int wave = threadIdx.x >> 6;
    if ((threadIdx.x & 63) == 0) {
        s[0][wave] = mnr; s[1][wave] = mxr; s[2][wave] = mnt; s[3][wave] = mxt;
    }
    __syncthreads();
    if (threadIdx.x == 0) {
        float a0 = s[0][0], a1 = s[1][0], a2 = s[2][0], a3 = s[3][0];
        #pragma unroll
        for (int w = 1; w < 4; ++w) {
            a0 = fminf(a0, s[0][w]);
            a1 = fmaxf(a1, s[1][w]);
            a2 = fminf(a2, s[2][w]);
            a3 = fmaxf(a3, s[3][w]);
        }
        atomicMin(&ws[0], f2o(a0));
        atomicMax(&ws[1], f2o(a1));
        atomicMin(&ws[2], f2o(a2));
        atomicMax(&ws[3], f2o(a3));
    }
}

// cubic B-spline weights for the 4 integer bins straddling s, u = frac(s)
__device__ __forceinline__ void bw4(float u, float w[4]) {
    float v = 1.0f - u;
    w[0] = v * v * v * (1.0f / 6.0f);                  // t = 1+u  -> (2-t)^3/6
    w[1] = (2.0f / 3.0f) - u * u + 0.5f * u * u * u;   // t = u
    w[2] = (2.0f / 3.0f) - v * v + 0.5f * v * v * v;   // t = 1-u
    w[3] = u * u * u * (1.0f / 6.0f);                  // t = 2-u  -> (2-t)^3/6
}

__global__ __launch_bounds__(256) void hist_kernel(
        const float* __restrict__ ref, const float* __restrict__ tar,
        const unsigned int* __restrict__ ws, float* __restrict__ out) {
    __shared__ float hist[HIST_SIZE];  // 16 KiB
    const int img = blockIdx.x / BLOCKS_PER_IMG;
    const int sub = blockIdx.x % BLOCKS_PER_IMG;
    for (int i = threadIdx.x; i < HIST_SIZE; i += 256) hist[i] = 0.0f;

    const float mn_r = o2f(ws[0]);
    const float sc_r = 64.0f / (o2f(ws[1]) - mn_r);
    const float mn_t = o2f(ws[2]);
    const float sc_t = 64.0f / (o2f(ws[3]) - mn_t);
    __syncthreads();

    const int pixPerBlock = NPIX / BLOCKS_PER_IMG;  // 2048
    const int base = img * NPIX + sub * pixPerBlock;
    const float4* r4 = (const float4*)(ref + base);
    const float4* t4 = (const float4*)(tar + base);
    for (int i = threadIdx.x; i < pixPerBlock / 4; i += 256) {
        float4 rv = r4[i];
        float4 tv = t4[i];
        float rs[4] = {rv.x, rv.y, rv.z, rv.w};
        float ts[4] = {tv.x, tv.y, tv.z, tv.w};
        #pragma unroll
        for (int p = 0; p < 4; ++p) {
            float r = (rs[p] - mn_r) * sc_r;  // in [0, 64]
            float t = (ts[p] - mn_t) * sc_t;
            float fr = floorf(r); int ir = (int)fr - 1; float ur = r - fr;
            float ft = floorf(t); int it = (int)ft - 1; float ut = t - ft;
            float wr[4], wt[4];
            bw4(ur, wr);
            bw4(ut, wt);
            #pragma unroll
            for (int a = 0; a < 4; ++a) {
                int br = ir + a;
                if (br < 0 || br >= NUM_BINS) continue;  // out-of-range bin: reference has no such bin
                float wra = wr[a];
                #pragma unroll
                for (int b = 0; b < 4; ++b) {
                    int bt = it + b;
                    if (bt < 0 || bt >= NUM_BINS) continue;
                    atomicAdd(&hist[br * NUM_BINS + bt], wra * wt[b]);
                }
            }
        }
    }
    __syncthreads();
    float* o = out + img * HIST_SIZE;
    for (int i = threadIdx.x; i < HIST_SIZE; i += 256) {
        float h = hist[i];
        if (h != 0.0f) atomicAdd(&o[i], h * 4096.0f);  // x4096 = 1/EPS^2
    }
}

extern "C" void kernel_launch(void* const* d_in, const int* in_sizes, int n_in,
                              void* d_out, int out_size, void* d_ws, size_t ws_size,
                              hipStream_t stream) {
    const float* ref = (const float*)d_in[0];
    const float* tar = (const float*)d_in[1];
    // d_in[2]/d_in[3] (bins) are arange(64)/64 by construction — folded into index math.
    float* out = (float*)d_out;
    unsigned int* ws = (unsigned int*)d_ws;

    init_kernel<<<(OUT_ELEMS + 255) / 256, 256, 0, stream>>>(out, ws);
    minmax_kernel<<<512, 256, 0, stream>>>((const float4*)ref, (const float4*)tar, ws);
    hist_kernel<<<NIMG * BLOCKS_PER_IMG, 256, 0, stream>>>(ref, tar, ws, out);
}

// Round 2
// 152.110 us; speedup vs baseline: 1.1343x; 1.1343x over previous
//
#include <hip/hip_runtime.h>

#define NUM_BINS 64
#define NPIX (256 * 256)
#define NIMG 16
#define HIST_SIZE (NUM_BINS * NUM_BINS)
#define OUT_ELEMS (NIMG * HIST_SIZE)

// ---- fast path geometry ----
#define MM_BLOCKS 512        // min/max partial blocks
#define MM_THREADS 256
#define SUBS 32              // hist blocks per image
#define H_BLOCKS (NIMG * SUBS)   // 512
#define H_THREADS 512
#define PIX_PER_BLOCK (NPIX / SUBS)  // 2048

// ws layout (fast path):
//   [0, MM_BLOCKS) float4              : min/max partials (mnr, mxr, mnt, mxt)
//   then H_BLOCKS * HIST_SIZE float    : per-block histogram partials

// cubic B-spline weights for the 4 integer bins straddling s, u = frac(s)
__device__ __forceinline__ void bw4(float u, float w[4]) {
    float v = 1.0f - u;
    w[0] = v * v * v * (1.0f / 6.0f);                  // t = 1+u
    w[1] = (2.0f / 3.0f) - u * u + 0.5f * u * u * u;   // t = u
    w[2] = (2.0f / 3.0f) - v * v + 0.5f * v * v * v;   // t = 1-u
    w[3] = u * u * u * (1.0f / 6.0f);                  // t = 2-u
}

// ================= K1: per-block min/max partials (no atomics) =================
__global__ __launch_bounds__(MM_THREADS) void minmax_part(
        const float4* __restrict__ ref4, const float4* __restrict__ tar4,
        float4* __restrict__ mmpart) {
    const int tid = blockIdx.x * MM_THREADS + threadIdx.x;
    const int stride = MM_BLOCKS * MM_THREADS;
    const int n4 = (NIMG * NPIX) / 4;
    float mnr = 3.0e38f, mxr = -3.0e38f, mnt = 3.0e38f, mxt = -3.0e38f;
    #pragma unroll 4
    for (int i = tid; i < n4; i += stride) {
        float4 a = ref4[i];
        float4 b = tar4[i];
        mnr = fminf(mnr, fminf(fminf(a.x, a.y), fminf(a.z, a.w)));
        mxr = fmaxf(mxr, fmaxf(fmaxf(a.x, a.y), fmaxf(a.z, a.w)));
        mnt = fminf(mnt, fminf(fminf(b.x, b.y), fminf(b.z, b.w)));
        mxt = fmaxf(mxt, fmaxf(fmaxf(b.x, b.y), fmaxf(b.z, b.w)));
    }
    #pragma unroll
    for (int off = 32; off > 0; off >>= 1) {
        mnr = fminf(mnr, __shfl_down(mnr, off));
        mxr = fmaxf(mxr, __shfl_down(mxr, off));
        mnt = fminf(mnt, __shfl_down(mnt, off));
        mxt = fmaxf(mxt, __shfl_down(mxt, off));
    }
    __shared__ float s[4][MM_THREADS / 64];
    const int wave = threadIdx.x >> 6;
    if ((threadIdx.x & 63) == 0) {
        s[0][wave] = mnr; s[1][wave] = mxr; s[2][wave] = mnt; s[3][wave] = mxt;
    }
    __syncthreads();
    if (threadIdx.x == 0) {
        float a0 = s[0][0], a1 = s[1][0], a2 = s[2][0], a3 = s[3][0];
        #pragma unroll
        for (int w = 1; w < MM_THREADS / 64; ++w) {
            a0 = fminf(a0, s[0][w]);
            a1 = fmaxf(a1, s[1][w]);
            a2 = fminf(a2, s[2][w]);
            a3 = fmaxf(a3, s[3][w]);
        }
        mmpart[blockIdx.x] = make_float4(a0, a1, a2, a3);
    }
}

// ================= K2: LDS hist -> private partial in ws (no global atomics) ===
__global__ __launch_bounds__(H_THREADS) void hist_part(
        const float* __restrict__ ref, const float* __restrict__ tar,
        const float4* __restrict__ mmpart, float* __restrict__ part) {
    __shared__ float hist[HIST_SIZE];   // 16 KiB
    __shared__ float4 smm[H_THREADS / 64];
    for (int i = threadIdx.x; i < HIST_SIZE; i += H_THREADS) hist[i] = 0.0f;

    // re-reduce the MM_BLOCKS min/max partials (L2-hot, 8 KB)
    float4 v = make_float4(3.0e38f, -3.0e38f, 3.0e38f, -3.0e38f);
    if (threadIdx.x < MM_BLOCKS) v = mmpart[threadIdx.x];
    #pragma unroll
    for (int off = 32; off > 0; off >>= 1) {
        v.x = fminf(v.x, __shfl_down(v.x, off));
        v.y = fmaxf(v.y, __shfl_down(v.y, off));
        v.z = fminf(v.z, __shfl_down(v.z, off));
        v.w = fmaxf(v.w, __shfl_down(v.w, off));
    }
    if ((threadIdx.x & 63) == 0) smm[threadIdx.x >> 6] = v;
    __syncthreads();   // covers hist zero-init AND smm
    float mn_r = 3.0e38f, mx_r = -3.0e38f, mn_t = 3.0e38f, mx_t = -3.0e38f;
    #pragma unroll
    for (int w = 0; w < H_THREADS / 64; ++w) {
        mn_r = fminf(mn_r, smm[w].x);
        mx_r = fmaxf(mx_r, smm[w].y);
        mn_t = fminf(mn_t, smm[w].z);
        mx_t = fmaxf(mx_t, smm[w].w);
    }
    const float sc_r = 64.0f / (mx_r - mn_r);
    const float sc_t = 64.0f / (mx_t - mn_t);

    const int img = blockIdx.x / SUBS;
    const int sub = blockIdx.x % SUBS;
    const int base = img * NPIX + sub * PIX_PER_BLOCK;
    const float4* r4 = (const float4*)(ref + base);
    const float4* t4 = (const float4*)(tar + base);
    for (int i = threadIdx.x; i < PIX_PER_BLOCK / 4; i += H_THREADS) {
        float4 rv = r4[i];
        float4 tv = t4[i];
        float rs[4] = {rv.x, rv.y, rv.z, rv.w};
        float ts[4] = {tv.x, tv.y, tv.z, tv.w};
        #pragma unroll
        for (int p = 0; p < 4; ++p) {
            float r = (rs[p] - mn_r) * sc_r;  // in [0, 64]
            float t = (ts[p] - mn_t) * sc_t;
            float fr = floorf(r); int ir = (int)fr - 1; float ur = r - fr;
            float ft = floorf(t); int it = (int)ft - 1; float ut = t - ft;
            float wr[4], wt[4];
            bw4(ur, wr);
            bw4(ut, wt);
            #pragma unroll
            for (int a = 0; a < 4; ++a) {
                int br = ir + a;
                if (br < 0 || br >= NUM_BINS) continue;
                float wra = wr[a];
                #pragma unroll
                for (int b = 0; b < 4; ++b) {
                    int bt = it + b;
                    if (bt < 0 || bt >= NUM_BINS) continue;
                    atomicAdd(&hist[br * NUM_BINS + bt], wra * wt[b]);
                }
            }
        }
    }
    __syncthreads();
    // coalesced float4 flush of the private histogram
    float4* dst = (float4*)(part + (size_t)blockIdx.x * HIST_SIZE);
    const float4* h4 = (const float4*)hist;
    for (int i = threadIdx.x; i < HIST_SIZE / 4; i += H_THREADS) dst[i] = h4[i];
}

// ================= K3: reduce SUBS partials per image, scale, store ============
__global__ __launch_bounds__(256) void reduce_k(
        const float* __restrict__ part, float* __restrict__ out) {
    const int i = blockIdx.x * 256 + threadIdx.x;  // 0 .. OUT_ELEMS
    const int img = i >> 12;          // /4096
    const int c = i & (HIST_SIZE - 1);
    const float* p = part + (size_t)(img * SUBS) * HIST_SIZE + c;
    float sum = 0.0f;
    #pragma unroll
    for (int s = 0; s < SUBS; ++s) sum += p[(size_t)s * HIST_SIZE];
    out[i] = sum * 4096.0f;  // 1/EPS^2
}

// ======================= fallback path (global atomics) ========================
__device__ __forceinline__ unsigned int f2o(float f) {
    unsigned int b = __float_as_uint(f);
    return (b & 0x80000000u) ? ~b : (b | 0x80000000u);
}
__device__ __forceinline__ float o2f(unsigned int u) {
    return __uint_as_float((u & 0x80000000u) ? (u ^ 0x80000000u) : ~u);
}

__global__ void init_kernel(float* __restrict__ out, unsigned int* __restrict__ ws) {
    int i = blockIdx.x * blockDim.x + threadIdx.x;
    if (i < OUT_ELEMS) out[i] = 0.0f;
    if (i == 0) {
        ws[0] = 0xFFFFFFFFu; ws[1] = 0u;
        ws[2] = 0xFFFFFFFFu; ws[3] = 0u;
    }
}

__global__ __launch_bounds__(256) void minmax_atomic(
        const float4* __restrict__ ref4, const float4* __restrict__ tar4,
        unsigned int* __restrict__ ws) {
    const int tid = blockIdx.x * blockDim.x + threadIdx.x;
    const int stride = gridDim.x * blockDim.x;
    const int n4 = (NIMG * NPIX) / 4;
    float mnr = 3.0e38f, mxr = -3.0e38f, mnt = 3.0e38f, mxt = -3.0e38f;
    for (int i = tid; i < n4; i += stride) {
        float4 a = ref4[i];
        float4 b = tar4[i];
        mnr = fminf(mnr, fminf(fminf(a.x, a.y), fminf(a.z, a.w)));
        mxr = fmaxf(mxr, fmaxf(fmaxf(a.x, a.y), fmaxf(a.z, a.w)));
        mnt = fminf(mnt, fminf(fminf(b.x, b.y), fminf(b.z, b.w)));
        mxt = fmaxf(mxt, fmaxf(fmaxf(b.x, b.y), fmaxf(b.z, b.w)));
    }
    #pragma unroll
    for (int off = 32; off > 0; off >>= 1) {
        mnr = fminf(mnr, __shfl_down(mnr, off));
        mxr = fmaxf(mxr, __shfl_down(mxr, off));
        mnt = fminf(mnt, __shfl_down(mnt, off));
        mxt = fmaxf(mxt, __shfl_down(mxt, off));
    }
    __shared__ float s[4][4];
    const int wave = threadIdx.x >> 6;
    if ((threadIdx.x & 63) == 0) {
        s[0][wave] = mnr; s[1][wave] = mxr; s[2][wave] = mnt; s[3][wave] = mxt;
    }
    __syncthreads();
    if (threadIdx.x == 0) {
        float a0 = s[0][0], a1 = s[1][0], a2 = s[2][0], a3 = s[3][0];
        #pragma unroll
        for (int w = 1; w < 4; ++w) {
            a0 = fminf(a0, s[0][w]); a1 = fmaxf(a1, s[1][w]);
            a2 = fminf(a2, s[2][w]); a3 = fmaxf(a3, s[3][w]);
        }
        atomicMin(&ws[0], f2o(a0));
        atomicMax(&ws[1], f2o(a1));
        atomicMin(&ws[2], f2o(a2));
        atomicMax(&ws[3], f2o(a3));
    }
}

__global__ __launch_bounds__(256) void hist_atomic(
        const float* __restrict__ ref, const float* __restrict__ tar,
        const unsigned int* __restrict__ ws, float* __restrict__ out) {
    __shared__ float hist[HIST_SIZE];
    const int img = blockIdx.x / 32;
    const int sub = blockIdx.x % 32;
    for (int i = threadIdx.x; i < HIST_SIZE; i += 256) hist[i] = 0.0f;
    const float mn_r = o2f(ws[0]);
    const float sc_r = 64.0f / (o2f(ws[1]) - mn_r);
    const float mn_t = o2f(ws[2]);
    const float sc_t = 64.0f / (o2f(ws[3]) - mn_t);
    __syncthreads();
    const int ppb = NPIX / 32;
    const int base = img * NPIX + sub * ppb;
    const float4* r4 = (const float4*)(ref + base);
    const float4* t4 = (const float4*)(tar + base);
    for (int i = threadIdx.x; i < ppb / 4; i += 256) {
        float4 rv = r4[i];
        float4 tv = t4[i];
        float rs[4] = {rv.x, rv.y, rv.z, rv.w};
        float ts[4] = {tv.x, tv.y, tv.z, tv.w};
        #pragma unroll
        for (int p = 0; p < 4; ++p) {
            float r = (rs[p] - mn_r) * sc_r;
            float t = (ts[p] - mn_t) * sc_t;
            float fr = floorf(r); int ir = (int)fr - 1; float ur = r - fr;
            float ft = floorf(t); int it = (int)ft - 1; float ut = t - ft;
            float wr[4], wt[4];
            bw4(ur, wr);
            bw4(ut, wt);
            #pragma unroll
            for (int a = 0; a < 4; ++a) {
                int br = ir + a;
                if (br < 0 || br >= NUM_BINS) continue;
                #pragma unroll
                for (int b = 0; b < 4; ++b) {
                    int bt = it + b;
                    if (bt < 0 || bt >= NUM_BINS) continue;
                    atomicAdd(&hist[br * NUM_BINS + bt], wr[a] * wt[b]);
                }
            }
        }
    }
    __syncthreads();
    float* o = out + img * HIST_SIZE;
    for (int i = threadIdx.x; i < HIST_SIZE; i += 256) {
        float h = hist[i];
        if (h != 0.0f) atomicAdd(&o[i], h * 4096.0f);
    }
}

extern "C" void kernel_launch(void* const* d_in, const int* in_sizes, int n_in,
                              void* d_out, int out_size, void* d_ws, size_t ws_size,
                              hipStream_t stream) {
    const float* ref = (const float*)d_in[0];
    const float* tar = (const float*)d_in[1];
    float* out = (float*)d_out;

    const size_t mm_bytes = MM_BLOCKS * sizeof(float4);
    const size_t part_bytes = (size_t)H_BLOCKS * HIST_SIZE * sizeof(float);

    if (ws_size >= mm_bytes + part_bytes) {
        float4* mmpart = (float4*)d_ws;
        float* part = (float*)((char*)d_ws + mm_bytes);
        minmax_part<<<MM_BLOCKS, MM_THREADS, 0, stream>>>(
            (const float4*)ref, (const float4*)tar, mmpart);
        hist_part<<<H_BLOCKS, H_THREADS, 0, stream>>>(ref, tar, mmpart, part);
        reduce_k<<<OUT_ELEMS / 256, 256, 0, stream>>>(part, out);
    } else {
        unsigned int* ws = (unsigned int*)d_ws;
        init_kernel<<<(OUT_ELEMS + 255) / 256, 256, 0, stream>>>(out, ws);
        minmax_atomic<<<512, 256, 0, stream>>>(
            (const float4*)ref, (const float4*)tar, ws);
        hist_atomic<<<NIMG * 32, 256, 0, stream>>>(ref, tar, ws, out);
    }
}

// Round 3
// 84.827 us; speedup vs baseline: 2.0340x; 1.7932x over previous
//
#include <hip/hip_runtime.h>

#define NUM_BINS 64
#define NPIX (256 * 256)
#define NIMG 16
#define HIST_SIZE (NUM_BINS * NUM_BINS)
#define OUT_ELEMS (NIMG * HIST_SIZE)

#define MM_BLOCKS 256
#define MM_THREADS 256

#define SUBS 32                      // hist blocks per image
#define H_BLOCKS (NIMG * SUBS)       // 512
#define H_THREADS 256                // 4 waves
#define PPB (NPIX / SUBS)            // 2048 px per block
#define PPW (PPB / 4)                // 512 px per wave
#define STEPS (PPW / 32)             // 16 k-steps of 32 px

#define TROWS 68                     // 64 bins + 1 top border + 3 bottom border
#define TCOLS 40                     // K=32 + 8 pad (breaks 128B bank period)
#define TSIZE (TROWS * TCOLS)        // ushorts per matrix tile
#define WREG (2 * TSIZE)             // per-wave region (A + B)

typedef __attribute__((ext_vector_type(8))) short bf16x8;
typedef __attribute__((ext_vector_type(4))) float f32x4;

__device__ __forceinline__ unsigned short f2bf(float f) {
    unsigned int u = __float_as_uint(f);
    unsigned int r = (u + 0x7FFFu + ((u >> 16) & 1u)) >> 16;  // RNE; weights are normal, >=0
    return (unsigned short)r;
}

// ================= K1: per-block min/max partials =================
__global__ __launch_bounds__(MM_THREADS) void minmax_part(
        const float4* __restrict__ ref4, const float4* __restrict__ tar4,
        float4* __restrict__ mmpart) {
    const int tid = blockIdx.x * MM_THREADS + threadIdx.x;
    const int stride = MM_BLOCKS * MM_THREADS;
    const int n4 = (NIMG * NPIX) / 4;
    float mnr = 3.0e38f, mxr = -3.0e38f, mnt = 3.0e38f, mxt = -3.0e38f;
    for (int i = tid; i < n4; i += stride) {
        float4 a = ref4[i];
        float4 b = tar4[i];
        mnr = fminf(mnr, fminf(fminf(a.x, a.y), fminf(a.z, a.w)));
        mxr = fmaxf(mxr, fmaxf(fmaxf(a.x, a.y), fmaxf(a.z, a.w)));
        mnt = fminf(mnt, fminf(fminf(b.x, b.y), fminf(b.z, b.w)));
        mxt = fmaxf(mxt, fmaxf(fmaxf(b.x, b.y), fmaxf(b.z, b.w)));
    }
    #pragma unroll
    for (int off = 32; off > 0; off >>= 1) {
        mnr = fminf(mnr, __shfl_down(mnr, off));
        mxr = fmaxf(mxr, __shfl_down(mxr, off));
        mnt = fminf(mnt, __shfl_down(mnt, off));
        mxt = fmaxf(mxt, __shfl_down(mxt, off));
    }
    __shared__ float s[4][MM_THREADS / 64];
    const int wave = threadIdx.x >> 6;
    if ((threadIdx.x & 63) == 0) {
        s[0][wave] = mnr; s[1][wave] = mxr; s[2][wave] = mnt; s[3][wave] = mxt;
    }
    __syncthreads();
    if (threadIdx.x == 0) {
        float a0 = s[0][0], a1 = s[1][0], a2 = s[2][0], a3 = s[3][0];
        #pragma unroll
        for (int w = 1; w < MM_THREADS / 64; ++w) {
            a0 = fminf(a0, s[0][w]);
            a1 = fmaxf(a1, s[1][w]);
            a2 = fminf(a2, s[2][w]);
            a3 = fmaxf(a3, s[3][w]);
        }
        mmpart[blockIdx.x] = make_float4(a0, a1, a2, a3);
    }
}

// ================= K2: MFMA joint histogram ==========================
// Per wave: private A/B operand tiles in LDS; lane<32 builds A (ref),
// lane>=32 builds B (tar) for the same 32 pixels. 16 MFMAs per 32 px.
__global__ __launch_bounds__(H_THREADS) void hist_gemm(
        const float* __restrict__ ref, const float* __restrict__ tar,
        const float4* __restrict__ mmpart, float* __restrict__ part) {
    __shared__ unsigned short tiles[4 * WREG];     // 43520 B
    __shared__ float cbuf[64 * 65];                // 16640 B (stride 65)
    __shared__ float4 smm[4];

    const int tid = threadIdx.x;
    const int wave = tid >> 6;
    const int lane = tid & 63;

    // ---- re-reduce the 256 min/max partials (one per thread) ----
    float4 v = mmpart[tid];
    #pragma unroll
    for (int off = 32; off > 0; off >>= 1) {
        v.x = fminf(v.x, __shfl_down(v.x, off));
        v.y = fmaxf(v.y, __shfl_down(v.y, off));
        v.z = fminf(v.z, __shfl_down(v.z, off));
        v.w = fmaxf(v.w, __shfl_down(v.w, off));
    }
    if (lane == 0) smm[wave] = v;

    // ---- zero this wave's tiles (per-wave private: no barrier needed) ----
    unsigned short* wbase = tiles + wave * WREG;
    {
        uint4 z = {0u, 0u, 0u, 0u};
        uint4* p = (uint4*)wbase;
        #pragma unroll
        for (int i = 0; i < (WREG / 8 + 63) / 64; ++i) {
            int idx = lane + i * 64;
            if (idx < WREG / 8) p[idx] = z;
        }
    }
    __syncthreads();  // smm ready

    const float mn_r = fminf(fminf(smm[0].x, smm[1].x), fminf(smm[2].x, smm[3].x));
    const float mx_r = fmaxf(fmaxf(smm[0].y, smm[1].y), fmaxf(smm[2].y, smm[3].y));
    const float mn_t = fminf(fminf(smm[0].z, smm[1].z), fminf(smm[2].z, smm[3].z));
    const float mx_t = fmaxf(fmaxf(smm[0].w, smm[1].w), fmaxf(smm[2].w, smm[3].w));

    const bool isRef = (lane < 32);
    const float mn = isRef ? mn_r : mn_t;
    const float sc = isRef ? (64.0f / (mx_r - mn_r)) : (64.0f / (mx_t - mn_t));
    const float* __restrict__ src = isRef ? ref : tar;
    unsigned short* T = wbase + (isRef ? 0 : TSIZE);
    const int col = lane & 31;

    const int img = blockIdx.x / SUBS;
    const int sub = blockIdx.x % SUBS;
    const int pbase = img * NPIX + sub * PPB + wave * PPW + col;

    f32x4 acc[4][4];
    #pragma unroll
    for (int a = 0; a < 4; ++a)
        #pragma unroll
        for (int b = 0; b < 4; ++b)
            acc[a][b] = (f32x4){0.f, 0.f, 0.f, 0.f};

    const unsigned short* aT = wbase;
    const unsigned short* bT = wbase + TSIZE;
    const int frow = (lane & 15) + 1;   // bin m -> physical row m+1
    const int fk = (lane >> 4) * 8;     // k slice within K=32

    int prev = 0;
    float vcur = src[pbase];
    for (int s = 0; s < STEPS; ++s) {
        float vnext = (s + 1 < STEPS) ? src[pbase + (s + 1) * 32] : 0.0f;
        float x = (vcur - mn) * sc;              // in [0, 64]
        float fx = floorf(x);
        int ib = (int)fx;                        // physical first row (= ir+1), 0..64
        float u = x - fx;
        float um = 1.0f - u;
        float w0 = um * um * um * (1.0f / 6.0f);
        float w1 = (2.0f / 3.0f) - u * u + 0.5f * u * u * u;
        float w2 = (2.0f / 3.0f) - um * um + 0.5f * um * um * um;
        float w3 = u * u * u * (1.0f / 6.0f);
        unsigned short h0 = f2bf(w0), h1 = f2bf(w1), h2 = f2bf(w2), h3 = f2bf(w3);

        // un-zero previous step's 4 cells, then scatter the new 4 (DS in-order per wave)
        unsigned short* tp = T + prev * TCOLS + col;
        tp[0] = 0; tp[TCOLS] = 0; tp[2 * TCOLS] = 0; tp[3 * TCOLS] = 0;
        unsigned short* tn = T + ib * TCOLS + col;
        tn[0] = h0; tn[TCOLS] = h1; tn[2 * TCOLS] = h2; tn[3 * TCOLS] = h3;
        prev = ib;

        bf16x8 af[4], bfr[4];
        #pragma unroll
        for (int mt = 0; mt < 4; ++mt)
            af[mt] = *(const bf16x8*)(aT + (mt * 16 + frow) * TCOLS + fk);
        #pragma unroll
        for (int nt = 0; nt < 4; ++nt)
            bfr[nt] = *(const bf16x8*)(bT + (nt * 16 + frow) * TCOLS + fk);
        #pragma unroll
        for (int mt = 0; mt < 4; ++mt)
            #pragma unroll
            for (int nt = 0; nt < 4; ++nt)
                acc[mt][nt] = __builtin_amdgcn_mfma_f32_16x16x32_bf16(
                    af[mt], bfr[nt], acc[mt][nt], 0, 0, 0);
        vcur = vnext;
    }

    // ---- combine the 4 waves' C into cbuf (C/D: col=lane&15, row=quad*4+reg) ----
    const int crow0 = (lane >> 4) * 4;
    const int ccol = lane & 15;
    for (int ph = 0; ph < 4; ++ph) {
        if (wave == ph) {
            #pragma unroll
            for (int mt = 0; mt < 4; ++mt)
                #pragma unroll
                for (int nt = 0; nt < 4; ++nt)
                    #pragma unroll
                    for (int r = 0; r < 4; ++r) {
                        int idx = (mt * 16 + crow0 + r) * 65 + nt * 16 + ccol;
                        if (ph == 0) cbuf[idx] = acc[mt][nt][r];
                        else cbuf[idx] += acc[mt][nt][r];
                    }
        }
        __syncthreads();
    }
    float* po = part + (size_t)blockIdx.x * HIST_SIZE;
    for (int c = tid; c < HIST_SIZE; c += H_THREADS)
        po[c] = cbuf[(c >> 6) * 65 + (c & 63)];
}

// ================= K3: reduce SUBS partials per image, scale, store ============
__global__ __launch_bounds__(256) void reduce_k(
        const float* __restrict__ part, float* __restrict__ out) {
    const int i = blockIdx.x * 256 + threadIdx.x;
    const int img = i >> 12;
    const int c = i & (HIST_SIZE - 1);
    const float* p = part + (size_t)(img * SUBS) * HIST_SIZE + c;
    float sum = 0.0f;
    #pragma unroll
    for (int s = 0; s < SUBS; ++s) sum += p[(size_t)s * HIST_SIZE];
    out[i] = sum * 4096.0f;  // 1/EPS^2
}

extern "C" void kernel_launch(void* const* d_in, const int* in_sizes, int n_in,
                              void* d_out, int out_size, void* d_ws, size_t ws_size,
                              hipStream_t stream) {
    const float* ref = (const float*)d_in[0];
    const float* tar = (const float*)d_in[1];
    float* out = (float*)d_out;

    float4* mmpart = (float4*)d_ws;
    float* part = (float*)((char*)d_ws + MM_BLOCKS * sizeof(float4));

    minmax_part<<<MM_BLOCKS, MM_THREADS, 0, stream>>>(
        (const float4*)ref, (const float4*)tar, mmpart);
    hist_gemm<<<H_BLOCKS, H_THREADS, 0, stream>>>(ref, tar, mmpart, part);
    reduce_k<<<OUT_ELEMS / 256, 256, 0, stream>>>(part, out);
}